// Round 6
// baseline (586.690 us; speedup 1.0000x reference)
//
#include <hip/hip_runtime.h>
#include <stdint.h>

// Bahdanau additive attention, MI355X (gfx950).
// B=32, T=2048, H=1024, U=1024. All inputs fp32; output context [B,H] fp32.
//
// R9 changes vs R8 (ONE lever):
//  - score_gemm switched from 16x16x32 MFMA to 32x32x16 MFMA. Four schedules
//    (R4/R6/R7/R8) all pinned at 859 TF / MfmaUtil 36% regardless of
//    pipelining or occupancy -> issue-bound, not schedule-bound. 32x32x16
//    halves MFMA instruction count AND ds_read count per FLOP, and the
//    32x32 pipe is faster per FLOP (2495 vs 2075 TF ubench). Simple
//    2-barrier loop, single-buffer 32 KiB LDS, 4+ blocks/CU.
//  - A/B frags: lane l -> row/col l&31, k8 = 2*kk + (l>>5) on the packed
//    [k8][row][8] layout. C/D: col = lane&31, row = (r&3)+8*(r>>2)+4*(l>>5).

#define B_ 32
#define T_ 2048
#define H_ 1024
#define U_ 1024
#define M_ (B_ * T_)

typedef __bf16 bf16x8 __attribute__((ext_vector_type(8)));
typedef float f32x16 __attribute__((ext_vector_type(16)));

__device__ __forceinline__ unsigned f2b(float f) {  // fp32 -> bf16 bits, RNE
  unsigned u = __float_as_uint(f);
  return (u + 0x7FFFu + ((u >> 16) & 1u)) >> 16;
}
__device__ __forceinline__ float b2f(unsigned short u) {
  return __uint_as_float(((unsigned)u) << 16);
}
__device__ __forceinline__ float fast_tanh(float x) {
  float xc = fminf(fmaxf(x, -12.f), 12.f);
  float t = exp2f(xc * 2.885390081777927f);  // 2*log2(e)
  return (t - 1.f) * __builtin_amdgcn_rcpf(t + 1.f);
}

#define AS1 __attribute__((address_space(1)))
#define AS3 __attribute__((address_space(3)))
__device__ __forceinline__ void gld_lds16(const void* g, void* l) {
  __builtin_amdgcn_global_load_lds((AS1 const void*)g, (AS3 void*)l, 16, 0, 0);
}

// ------------------------------------------------------------- prep
// Grid-partitioned fusion of four independent prologue tasks:
//   bx in [0,4096)     : conv_enc  (enc fp32 -> encA bf16 packed, LDS transpose)
//   bx in [4096,4608)  : conv_ua   (Ua fp32 -> Ub bf16 packed)
//   bx in [4608,5120)  : decproj   (dp4[hz][b][u] partials)
//   bx in [5120,5248)  : zero d_out (poisoned by harness; ctx_k atomicAdds)
__global__ __launch_bounds__(256) void prep_k(
    const float4* __restrict__ enc, uint4* __restrict__ outA,
    const float* __restrict__ Ua, uint4* __restrict__ Ub,
    const float* __restrict__ dh, const float* __restrict__ Wa,
    float* __restrict__ dp4, float* __restrict__ outz) {
  const int bx = blockIdx.x;
  const int tx = threadIdx.x;

  if (bx < 4096) {
    // ---- conv_enc: reads 16 rows (64 KB fp32), writes packed bf16.
    __shared__ uint4 L4[128 * 17];
    const int band = bx;
    const int mt = band >> 3;
    const int R = (band & 7) << 4;  // ml base within 128-row tile
    const float4* src = enc + (size_t)band * 4096;  // 16 rows * 256 float4
#pragma unroll
    for (int i = 0; i < 8; ++i) {
      int p = i * 256 + tx;  // pair index: row r, k8 chunk pc
      int r = p >> 7, pc = p & 127;
      float4 a = src[r * 256 + pc * 2];
      float4 b = src[r * 256 + pc * 2 + 1];
      uint4 o;
      o.x = f2b(a.x) | (f2b(a.y) << 16);
      o.y = f2b(a.z) | (f2b(a.w) << 16);
      o.z = f2b(b.x) | (f2b(b.y) << 16);
      o.w = f2b(b.z) | (f2b(b.w) << 16);
      L4[pc * 17 + r] = o;
    }
    __syncthreads();
    const int r2 = tx & 15, kq = (tx >> 4) & 3, w = tx >> 6;
#pragma unroll
    for (int j = 0; j < 8; ++j) {
      int k8 = j * 16 + w * 4 + kq;
      outA[((size_t)mt * 128 + k8) * 128 + R + r2] = L4[k8 * 17 + r2];
    }
  } else if (bx < 4608) {
    // ---- conv_ua: Ua [H][U] -> Ub [(H/8)][U][8] bf16, dense 16B writes.
    int id = (bx - 4096) * 256 + tx;  // 131072 = 128 h8 * 1024 u
    int h8 = id >> 10, u = id & 1023;
    const float* p = Ua + (size_t)(h8 << 3) * U_ + u;
    uint4 o;
    o.x = f2b(p[0]) | (f2b(p[U_]) << 16);
    o.y = f2b(p[2 * U_]) | (f2b(p[3 * U_]) << 16);
    o.z = f2b(p[4 * U_]) | (f2b(p[5 * U_]) << 16);
    o.w = f2b(p[6 * U_]) | (f2b(p[7 * U_]) << 16);
    Ub[(size_t)h8 * U_ + u] = o;
  } else if (bx < 5120) {
    // ---- decproj: dp4[hz][b][u] partial over 256-h chunk.
    int g = bx - 4608;  // 512 = 4 uc * 32 b * 4 hz
    const int u = (g & 3) * 256 + tx;
    const int b = (g >> 2) & 31, hz = g >> 7;
    const float* d = dh + b * H_ + hz * 256;
    const float* w = Wa + (size_t)(hz * 256) * U_ + u;
    float a0 = 0.f, a1 = 0.f, a2 = 0.f, a3 = 0.f;
#pragma unroll 4
    for (int h = 0; h < 256; h += 4) {
      a0 = fmaf(d[h + 0], w[(size_t)(h + 0) * U_], a0);
      a1 = fmaf(d[h + 1], w[(size_t)(h + 1) * U_], a1);
      a2 = fmaf(d[h + 2], w[(size_t)(h + 2) * U_], a2);
      a3 = fmaf(d[h + 3], w[(size_t)(h + 3) * U_], a3);
    }
    dp4[((hz * B_ + b) * U_) + u] = (a0 + a1) + (a2 + a3);
  } else {
    // ---- zero d_out (32768 floats).
    outz[(bx - 5120) * 256 + tx] = 0.f;
  }
}

// ------------------------------------------------------------- fused GEMM
// 128^2 tile, 2-barrier K-loop, gld_lds-direct staging, 32x32x16 MFMA.
// 4 waves (2M x 2N), wave = 64x64 = 2x2 frags of 32x32. Per K-64 step:
// 4 kk-substeps (K=16 each): 2 A + 2 B ds_read_b128, 4 MFMA.
// XCD swizzle: bx = (s<<6)|(m3<<3)|x -> mtile = s*8+x, ntile = m3; A-panel
// (256 KiB) L2-resident across its 8 ntile-blocks.
__global__ __launch_bounds__(256, 4) void score_gemm_k(
    const unsigned short* __restrict__ encA,  // packed [mt][k8][ml][8]
    const unsigned short* __restrict__ Ub,    // [k8][N][8]
    const float* __restrict__ dp4,            // [4][B][U]
    const float* __restrict__ Va,             // [U]
    float* __restrict__ score8)               // [8][M]
{
  __shared__ union {
    struct {
      alignas(16) unsigned short As[8][128][8];  // [k8][m][j] 16 KiB
      alignas(16) unsigned short Bs[8][128][8];  // [k8][n][j] 16 KiB
    } t;
    float sred[128][2];  // epilogue scratch (1 KiB)
  } sm;

  const int bx = blockIdx.x;
  const int mtile = ((bx >> 6) << 3) | (bx & 7), ntile = (bx >> 3) & 7;
  const int m0 = mtile << 7, n0 = ntile << 7;
  const int tid = threadIdx.x;
  const int wv = tid >> 6, ln = tid & 63;
  const int wm = wv & 1, wn = wv >> 1;  // 2 x 2 wave grid, wave = 64x64
  const int l32 = ln & 31, lh = ln >> 5;

  f32x16 acc[2][2];
#pragma unroll
  for (int i = 0; i < 2; ++i)
#pragma unroll
    for (int j = 0; j < 2; ++j)
#pragma unroll
      for (int r = 0; r < 16; ++r) acc[i][j][r] = 0.f;

  const unsigned short* encT = encA + (size_t)mtile * (128 * 128 * 8);

  for (int k0 = 0; k0 < H_; k0 += 64) {
    __syncthreads();
#pragma unroll
    for (int c = 0; c < 4; ++c) {
      int chunk = (wv << 2) + c;  // 0..15
      int k8 = chunk >> 1, half = chunk & 1;
      const unsigned short* ga =
          encT + (((size_t)((k0 >> 3) + k8) * 128) + (half << 6) + ln) * 8;
      gld_lds16(ga, &sm.t.As[k8][half << 6][0]);
      const unsigned short* gb =
          Ub + (((size_t)((k0 >> 3) + k8) * U_) + n0 + (half << 6) + ln) * 8;
      gld_lds16(gb, &sm.t.Bs[k8][half << 6][0]);
    }
    __syncthreads();

#pragma unroll
    for (int kk = 0; kk < 4; ++kk) {
      const int k8b = (kk << 1) + lh;  // lane-half picks the k8 slot
      bf16x8 af[2], bf[2];
#pragma unroll
      for (int mi = 0; mi < 2; ++mi)
        af[mi] = *(const bf16x8*)&sm.t.As[k8b][(wm << 6) + (mi << 5) + l32][0];
#pragma unroll
      for (int ni = 0; ni < 2; ++ni)
        bf[ni] = *(const bf16x8*)&sm.t.Bs[k8b][(wn << 6) + (ni << 5) + l32][0];
#pragma unroll
      for (int mi = 0; mi < 2; ++mi)
#pragma unroll
        for (int ni = 0; ni < 2; ++ni)
          acc[mi][ni] = __builtin_amdgcn_mfma_f32_32x32x16_bf16(
              af[mi], bf[ni], acc[mi][ni], 0, 0, 0);
    }
  }

  // Epilogue: v = sum_ni tanh(acc + dp) * Va; shfl-reduce over the 32 cols
  // (5 xor levels within each 32-lane half), cross-wn via 1 KiB sred.
  // C/D layout (32x32): col = l32, row = (r&3) + 8*(r>>2) + 4*lh.
  const int bq = m0 >> 11;  // batch (tile never straddles b)
  float va[2], dpv[2];
#pragma unroll
  for (int ni = 0; ni < 2; ++ni) {
    int col = n0 + (wn << 6) + (ni << 5) + l32;
    va[ni] = Va[col];
    dpv[ni] = dp4[bq * U_ + col] + dp4[B_ * U_ + bq * U_ + col] +
              dp4[2 * B_ * U_ + bq * U_ + col] +
              dp4[3 * B_ * U_ + bq * U_ + col];
  }
  __syncthreads();  // LDS tile reads done; reuse as sred
#pragma unroll
  for (int mi = 0; mi < 2; ++mi) {
#pragma unroll
    for (int r = 0; r < 16; ++r) {
      float v = fast_tanh(acc[mi][0][r] + dpv[0]) * va[0] +
                fast_tanh(acc[mi][1][r] + dpv[1]) * va[1];
#pragma unroll
      for (int off = 1; off < 32; off <<= 1) v += __shfl_xor(v, off);
      if (l32 == 0) {
        int row = (wm << 6) + (mi << 5) + (r & 3) + ((r >> 2) << 3) + (lh << 2);
        sm.sred[row][wn] = v;
      }
    }
  }
  __syncthreads();
  if (tid < 128) {
    score8[(size_t)ntile * M_ + m0 + tid] = sm.sred[tid][0] + sm.sred[tid][1];
  }
}

// ------------------------------------------------------------- context
// Per (b, bt) block: recompute b's softmax from score8 (L2-resident), then
// accumulate this block's 128-t slice of context and atomicAdd into
// out[b][h] (zeroed by prep_k).
__global__ __launch_bounds__(256) void ctx_k(const uint4* __restrict__ encA,
                                             const float* __restrict__ score8,
                                             float* __restrict__ out) {
  const int b = blockIdx.y, bt = blockIdx.x, tid = threadIdx.x;
  __shared__ float s_sc[2048];   // summed scores for this b (8 KB)
  __shared__ float a_s[128];     // alpha slice for this bt
  __shared__ float red[4];
  __shared__ float cred[2][128][8];

  // 1) sum the 8 ntile slabs; keep in regs + LDS.
  float4 v0 = {0.f, 0.f, 0.f, 0.f}, v1 = {0.f, 0.f, 0.f, 0.f};
#pragma unroll
  for (int k = 0; k < 8; ++k) {
    const float4* p = (const float4*)(score8 + (size_t)k * M_ + b * T_);
    float4 x0 = p[tid * 2], x1 = p[tid * 2 + 1];
    v0.x += x0.x; v0.y += x0.y; v0.z += x0.z; v0.w += x0.w;
    v1.x += x1.x; v1.y += x1.y; v1.z += x1.z; v1.w += x1.w;
  }
  ((float4*)s_sc)[tid * 2] = v0;
  ((float4*)s_sc)[tid * 2 + 1] = v1;

  // 2) block max.
  float m = fmaxf(fmaxf(fmaxf(v0.x, v0.y), fmaxf(v0.z, v0.w)),
                  fmaxf(fmaxf(v1.x, v1.y), fmaxf(v1.z, v1.w)));
#pragma unroll
  for (int off = 32; off >= 1; off >>= 1) m = fmaxf(m, __shfl_xor(m, off));
  if ((tid & 63) == 0) red[tid >> 6] = m;
  __syncthreads();
  m = fmaxf(fmaxf(red[0], red[1]), fmaxf(red[2], red[3]));
  __syncthreads();

  // 3) block sum of exp.
  const float l2e = 1.4426950408889634f;
  float sum = exp2f((v0.x - m) * l2e) + exp2f((v0.y - m) * l2e) +
              exp2f((v0.z - m) * l2e) + exp2f((v0.w - m) * l2e) +
              exp2f((v1.x - m) * l2e) + exp2f((v1.y - m) * l2e) +
              exp2f((v1.z - m) * l2e) + exp2f((v1.w - m) * l2e);
#pragma unroll
  for (int off = 32; off >= 1; off >>= 1) sum += __shfl_xor(sum, off);
  if ((tid & 63) == 0) red[tid >> 6] = sum;
  __syncthreads();
  const float inv = 1.f / (red[0] + red[1] + red[2] + red[3]);

  // 4) alpha slice for this block's 128 t's.
  if (tid < 128) a_s[tid] = exp2f((s_sc[bt * 128 + tid] - m) * l2e) * inv;
  __syncthreads();

  // 5) context partial over this 128-t slice.
  const int tx = tid & 127, th = tid >> 7;
  const int mt = b * 16 + bt;
  const uint4* base = encA + ((size_t)mt * 128 + tx) * 128 + th * 64;
  float a[8];
#pragma unroll
  for (int j = 0; j < 8; ++j) a[j] = 0.f;
#pragma unroll 4
  for (int i = 0; i < 64; ++i) {
    float w = a_s[th * 64 + i];
    uint4 e = base[i];
    a[0] = fmaf(w, b2f((unsigned short)e.x), a[0]);
    a[1] = fmaf(w, b2f((unsigned short)(e.x >> 16)), a[1]);
    a[2] = fmaf(w, b2f((unsigned short)e.y), a[2]);
    a[3] = fmaf(w, b2f((unsigned short)(e.y >> 16)), a[3]);
    a[4] = fmaf(w, b2f((unsigned short)e.z), a[4]);
    a[5] = fmaf(w, b2f((unsigned short)(e.z >> 16)), a[5]);
    a[6] = fmaf(w, b2f((unsigned short)e.w), a[6]);
    a[7] = fmaf(w, b2f((unsigned short)(e.w >> 16)), a[7]);
  }
#pragma unroll
  for (int j = 0; j < 8; ++j) cred[th][tx][j] = a[j];
  __syncthreads();
  if (th == 0) {
    float* o = out + (size_t)b * H_ + tx * 8;
#pragma unroll
    for (int j = 0; j < 8; ++j)
      atomicAdd(&o[j], cred[0][tx][j] + cred[1][tx][j]);
  }
}

// ------------------------------------------------------------- launch
extern "C" void kernel_launch(void* const* d_in, const int* in_sizes, int n_in,
                              void* d_out, int out_size, void* d_ws, size_t ws_size,
                              hipStream_t stream) {
  const float* enc = (const float*)d_in[0];
  const float* dh  = (const float*)d_in[1];
  const float* Wa  = (const float*)d_in[2];
  const float* Ua  = (const float*)d_in[3];
  const float* Va  = (const float*)d_in[4];

  char* ws = (char*)d_ws;
  unsigned short* encA = (unsigned short*)ws;                     // 128 MiB
  unsigned short* Ub   = (unsigned short*)(ws + 134217728);       // 2 MiB
  float* dp4    = (float*)(ws + 136314880);                       // 512 KiB
  float* score8 = (float*)(ws + 136839168);                       // 2 MiB

  prep_k<<<5248, 256, 0, stream>>>((const float4*)enc, (uint4*)encA, Ua,
                                   (uint4*)Ub, dh, Wa, dp4, (float*)d_out);
  score_gemm_k<<<4096, 256, 0, stream>>>(encA, Ub, dp4, Va, score8);
  ctx_k<<<dim3(16, 32), 256, 0, stream>>>((const uint4*)encA, score8,
                                          (float*)d_out);
}